// Round 1
// 2319.938 us; speedup vs baseline: 1.0328x; 1.0328x over previous
//
#include <hip/hip_runtime.h>
#include <hip/hip_bf16.h>
#include <stdint.h>

typedef __bf16 bf16x8 __attribute__((ext_vector_type(8)));
typedef float  f32x4  __attribute__((ext_vector_type(4)));

#define MFMA16(a, b, c) __builtin_amdgcn_mfma_f32_16x16x32_bf16((a), (b), (c), 0, 0, 0)

// ---------------------------------------------------------------------------
// Generic fused node GEMM: out = [swish](A @ W + bias) [+ res]
// A = [A0 | A1] (K = 128 or 256), each half bf16 or f32 (flags a0f/a1f).
// Weights are f32 in global, staged transposed+bf16 in LDS ([n][k], pitch K+8).
// Block: 256 thr = 4 waves; 64 rows/block; wave w handles rows w*16..w*16+15.
// ---------------------------------------------------------------------------
__global__ __launch_bounds__(256) void node_gemm(
    const void* __restrict__ A0, int a0f, const void* __restrict__ A1v, int a1f,
    const float* __restrict__ W0, const float* __restrict__ W1,
    const float* __restrict__ bias, const void* __restrict__ resv, int resf,
    void* __restrict__ outv, int outf, int nrows, int do_swish)
{
    extern __shared__ char smem[];
    const int K  = A1v ? 256 : 128;
    const int KP = K + 8;
    __bf16* WT = (__bf16*)smem;                       // [128][KP]
    int tid = threadIdx.x;

    for (int i = tid; i < 16384; i += 256) { int k = i >> 7, n = i & 127; WT[n * KP + k] = (__bf16)W0[i]; }
    if (W1)
        for (int i = tid; i < 16384; i += 256) { int k = i >> 7, n = i & 127; WT[n * KP + 128 + k] = (__bf16)W1[i]; }
    __syncthreads();

    int wave = tid >> 6, lane = tid & 63, m = lane & 15, q = lane >> 4, kg = q * 8;
    int rowA = blockIdx.x * 64 + wave * 16 + m;
    if (rowA >= nrows) rowA = nrows - 1;              // clamp; stores are guarded

    f32x4 acc[8];
#pragma unroll
    for (int i = 0; i < 8; ++i) acc[i] = (f32x4){0.f, 0.f, 0.f, 0.f};

    for (int k0 = 0; k0 < K; k0 += 32) {
        int kk = k0 + kg;
        const void* Ap = A0; int isf = a0f; int ko = kk;
        if (kk >= 128) { Ap = A1v; isf = a1f; ko = kk - 128; }
        bf16x8 af;
        if (isf) {
            const float* p = (const float*)Ap + (size_t)rowA * 128 + ko;
            f32x4 u0 = *(const f32x4*)p;
            f32x4 u1 = *(const f32x4*)(p + 4);
#pragma unroll
            for (int j = 0; j < 4; ++j) { af[j] = (__bf16)u0[j]; af[4 + j] = (__bf16)u1[j]; }
        } else {
            af = *(const bf16x8*)((const __bf16*)Ap + (size_t)rowA * 128 + ko);
        }
#pragma unroll
        for (int ct = 0; ct < 8; ++ct) {
            bf16x8 bfr = *(const bf16x8*)(WT + (ct * 16 + m) * KP + kk);
            acc[ct] = MFMA16(af, bfr, acc[ct]);
        }
    }

    int rb = blockIdx.x * 64 + wave * 16 + q * 4;
#pragma unroll
    for (int ct = 0; ct < 8; ++ct) {
        int col = ct * 16 + m;
        float bb = bias ? bias[col] : 0.f;
#pragma unroll
        for (int rg = 0; rg < 4; ++rg) {
            int r = rb + rg;
            if (r < nrows) {
                float v = acc[ct][rg] + bb;
                if (do_swish) v = v / (1.f + __expf(-v));
                if (resv) v += resf ? ((const float*)resv)[(size_t)r * 128 + col]
                                    : (float)((const __bf16*)resv)[(size_t)r * 128 + col];
                if (outf) ((float*)outv)[(size_t)r * 128 + col] = v;
                else      ((__bf16*)outv)[(size_t)r * 128 + col] = (__bf16)v;
            }
        }
    }
}

// ---------------------------------------------------------------------------
// Counting-sort of edges by dst (built once, reused by both convs).
// ---------------------------------------------------------------------------
__global__ __launch_bounds__(256) void k_hist(
    const int* __restrict__ eidx, int* __restrict__ cnt, int E_)
{
    int e = blockIdx.x * 256 + threadIdx.x;
    if (e < E_) atomicAdd(&cnt[eidx[E_ + e]], 1);
}

// Single-block exclusive scan in place (N ~ 50K: 49 chunks of 1024).
__global__ __launch_bounds__(1024) void k_scan(int* __restrict__ data, int n)
{
    __shared__ int wsum[16];
    __shared__ int wbase[16];
    __shared__ int carry_s;
    int tid = threadIdx.x, lane = tid & 63, wid = tid >> 6;
    if (tid == 0) carry_s = 0;
    __syncthreads();
    for (int base = 0; base < n; base += 1024) {
        int i = base + tid;
        int v = (i < n) ? data[i] : 0;
        int s = v;
#pragma unroll
        for (int off = 1; off < 64; off <<= 1) {
            int t = __shfl_up(s, off);
            if (lane >= off) s += t;
        }
        if (lane == 63) wsum[wid] = s;
        __syncthreads();
        if (tid == 0) {
            int acc = carry_s;
#pragma unroll
            for (int w = 0; w < 16; ++w) { wbase[w] = acc; acc += wsum[w]; }
            carry_s = acc;
        }
        __syncthreads();
        if (i < n) data[i] = wbase[wid] + s - v;      // exclusive
        __syncthreads();
    }
}

__global__ __launch_bounds__(256) void k_scatter(
    const int* __restrict__ eidx, int* __restrict__ wptr,
    int* __restrict__ sperm, int* __restrict__ ssrc, int* __restrict__ sdst, int E_)
{
    int e = blockIdx.x * 256 + threadIdx.x;
    if (e < E_) {
        int s = eidx[e], d = eidx[E_ + e];
        int p = atomicAdd(&wptr[d], 1);
        sperm[p] = e; ssrc[p] = s; sdst[p] = d;
    }
}

// ---------------------------------------------------------------------------
// Fused edge conv over DST-SORTED edges. Per 128-position tile:
//   T1 = feat[perm[tile]] @ W1      (K padded to K32 with zeros)
//   F  = T1 @ W2
//   MS = F * xh[src]   (f32, LDS, two 64-col passes)
//   per-wave serial segment-reduce over sorted dst -> ~1 atomic per run*col
// LDS overlay: stage1 {A1[128][AST] @0, WT1[64][AST] @128*AST*2}
//              stage2 {XHL[128][136] @0, T1L[128][72] @34816, WT2[128][72] @53248}
//              stage3 {MS f32 [128][68] @34816}   ints @71680. Total 73216 B.
// ---------------------------------------------------------------------------
template <int KF, int K32, int AST>
__global__ __launch_bounds__(256) void edge_conv(
    const float* __restrict__ feat, const float* __restrict__ W1g,
    const float* __restrict__ W2g, const __bf16* __restrict__ xh,
    const int* __restrict__ sperm, const int* __restrict__ ssrc,
    const int* __restrict__ sdst, float* __restrict__ agg, int E_)
{
    extern __shared__ char smem[];
    __bf16* A1  = (__bf16*)smem;                      // stage1
    __bf16* WT1 = (__bf16*)(smem + 128 * AST * 2);    // stage1
    __bf16* XHL = (__bf16*)smem;                      // stage2 overlay
    __bf16* T1L = (__bf16*)(smem + 34816);
    __bf16* WT2 = (__bf16*)(smem + 53248);
    float*  MS  = (float*)(smem + 34816);             // stage3 overlay (f32)
    int* sP = (int*)(smem + 71680);
    int* sS = sP + 128;
    int* sD = sP + 256;

    int tid = threadIdx.x;
    int p0  = blockIdx.x * 128;

    if (tid < 128) {
        int p = p0 + tid; int e = -1, s = 0, d = -1;
        if (p < E_) { e = sperm[p]; s = ssrc[p]; d = sdst[p]; }
        sP[tid] = e; sS[tid] = s; sD[tid] = d;
    }
    __syncthreads();

    // --- stage feature rows (gather by perm): f32 -> bf16 LDS ---
    for (int i = tid; i < 128 * KF; i += 256) {
        int r = i / KF, c = i - r * KF;
        int e = sP[r];
        float v = (e >= 0) ? feat[(size_t)e * KF + c] : 0.f;
        A1[r * AST + c] = (__bf16)v;
    }
    for (int i = tid; i < 128 * (K32 - KF); i += 256) {
        int r = i / (K32 - KF), c = KF + i - r * (K32 - KF);
        ((unsigned short*)A1)[r * AST + c] = 0;
    }
    // --- stage W1 transposed (f32 -> bf16) ---
    for (int i = tid; i < KF * 64; i += 256) { int k = i >> 6, n = i & 63; WT1[n * AST + k] = (__bf16)W1g[i]; }
    for (int i = tid; i < 64 * (K32 - KF); i += 256) {
        int n = i / (K32 - KF), k = KF + i - n * (K32 - KF);
        ((unsigned short*)WT1)[n * AST + k] = 0;
    }
    __syncthreads();

    int wave = tid >> 6, lane = tid & 63, m = lane & 15, q = lane >> 4, kg = q * 8;

    // --- stage1 MFMA: [128 x K32] @ [K32 x 64] ---
    f32x4 accT[2][4];
#pragma unroll
    for (int a = 0; a < 2; ++a)
#pragma unroll
        for (int b = 0; b < 4; ++b) accT[a][b] = (f32x4){0.f, 0.f, 0.f, 0.f};
#pragma unroll
    for (int k0 = 0; k0 < K32; k0 += 32) {
        bf16x8 a0 = *(const bf16x8*)(A1 + (wave * 32 + m) * AST + k0 + kg);
        bf16x8 a1 = *(const bf16x8*)(A1 + (wave * 32 + 16 + m) * AST + k0 + kg);
#pragma unroll
        for (int ct = 0; ct < 4; ++ct) {
            bf16x8 b = *(const bf16x8*)(WT1 + (ct * 16 + m) * AST + k0 + kg);
            accT[0][ct] = MFMA16(a0, b, accT[0][ct]);
            accT[1][ct] = MFMA16(a1, b, accT[1][ct]);
        }
    }
    __syncthreads();   // done with A1/WT1 regions

    // --- write T1 to LDS (bf16), gather xh rows, stage W2 transposed ---
#pragma unroll
    for (int rt = 0; rt < 2; ++rt)
#pragma unroll
        for (int ct = 0; ct < 4; ++ct)
#pragma unroll
            for (int rg = 0; rg < 4; ++rg) {
                int row = wave * 32 + rt * 16 + q * 4 + rg;
                int col = ct * 16 + m;
                T1L[row * 72 + col] = (__bf16)accT[rt][ct][rg];
            }
    for (int i2 = tid; i2 < 128 * 16; i2 += 256) {
        int r = i2 >> 4, c8 = (i2 & 15) * 8;
        *(bf16x8*)(XHL + r * 136 + c8) = *(const bf16x8*)(xh + (size_t)sS[r] * 128 + c8);
    }
    for (int i = tid; i < 64 * 128; i += 256) { int k = i >> 7, n = i & 127; WT2[n * 72 + k] = (__bf16)W2g[i]; }
    __syncthreads();

    // --- stage2 MFMA: [128 x 64] @ [64 x 128] ---
    f32x4 acc2[2][8];
#pragma unroll
    for (int a = 0; a < 2; ++a)
#pragma unroll
        for (int b = 0; b < 8; ++b) acc2[a][b] = (f32x4){0.f, 0.f, 0.f, 0.f};
#pragma unroll
    for (int k0 = 0; k0 < 64; k0 += 32) {
        bf16x8 a0 = *(const bf16x8*)(T1L + (wave * 32 + m) * 72 + k0 + kg);
        bf16x8 a1 = *(const bf16x8*)(T1L + (wave * 32 + 16 + m) * 72 + k0 + kg);
#pragma unroll
        for (int ct = 0; ct < 8; ++ct) {
            bf16x8 b = *(const bf16x8*)(WT2 + (ct * 16 + m) * 72 + k0 + kg);
            acc2[0][ct] = MFMA16(a0, b, acc2[0][ct]);
            acc2[1][ct] = MFMA16(a1, b, acc2[1][ct]);
        }
    }
    __syncthreads();   // T1L/WT2 dead; MS region free (XHL stays live)

    // --- stage3: MS = F * xh[src] (f32 LDS), segment-reduce sorted dst runs ---
#pragma unroll
    for (int half = 0; half < 2; ++half) {
#pragma unroll
        for (int rt = 0; rt < 2; ++rt)
#pragma unroll
            for (int c4 = 0; c4 < 4; ++c4) {
                int ct = half * 4 + c4;
#pragma unroll
                for (int rg = 0; rg < 4; ++rg) {
                    int row = wave * 32 + rt * 16 + q * 4 + rg;
                    int col = ct * 16 + m;
                    MS[row * 68 + c4 * 16 + m] = acc2[rt][ct][rg] * (float)XHL[row * 136 + col];
                }
            }
        __syncthreads();
        // per-wave serial scan over 32 sorted rows; one atomic per dst-run
        {
            int c = tid & 63, seg = tid >> 6, r0 = seg * 32;
            float ssum = 0.f;
            int cur = sD[r0];
            for (int r = r0; r < r0 + 32; ++r) {
                int d = sD[r];
                if (d != cur) {
                    if (cur >= 0) unsafeAtomicAdd(agg + (size_t)cur * 128 + half * 64 + c, ssum);
                    ssum = 0.f; cur = d;
                }
                ssum += MS[r * 68 + c];
            }
            if (cur >= 0) unsafeAtomicAdd(agg + (size_t)cur * 128 + half * 64 + c, ssum);
        }
        if (half == 0) __syncthreads();   // protect MS before second pass
    }
}

// ---------------------------------------------------------------------------
// GraphNorm stats: one block per graph (batch sorted -> binary search bounds).
// Emits meanms[g][c] = mean*ms and scalev[g][c] = norm_w * rsqrt(var+eps).
// ---------------------------------------------------------------------------
__device__ inline int lb_search(const int* a, int n, int v)
{
    int lo = 0, hi = n;
    while (lo < hi) { int mid = (lo + hi) >> 1; if (a[mid] < v) lo = mid + 1; else hi = mid; }
    return lo;
}

__global__ __launch_bounds__(256) void graph_stats(
    const float* __restrict__ h, const int* __restrict__ batch,
    const float* __restrict__ norm_w, const float* __restrict__ norm_ms,
    float* __restrict__ meanms, float* __restrict__ scalev, int Nn)
{
    int g = blockIdx.x, tid = threadIdx.x;
    int s = lb_search(batch, Nn, g);
    int e = lb_search(batch, Nn, g + 1);
    __shared__ float r1[256], r2[256];
    int c = tid & 127, half = tid >> 7;
    float S1 = 0.f, S2 = 0.f;
    for (int r = s + half; r < e; r += 2) {
        float v = h[(size_t)r * 128 + c];
        S1 += v; S2 += v * v;
    }
    r1[tid] = S1; r2[tid] = S2;
    __syncthreads();
    if (tid < 128) {
        float s1 = r1[tid] + r1[tid + 128];
        float s2 = r2[tid] + r2[tid + 128];
        float cnt = (float)((e - s) > 0 ? (e - s) : 1);
        float mean = s1 / cnt, E2 = s2 / cnt;
        float msv = norm_ms[tid];
        float mm = mean * msv;
        float var = E2 - 2.f * mm * mean + mm * mm;
        meanms[g * 128 + tid] = mm;
        scalev[g * 128 + tid] = norm_w[tid] * rsqrtf(var + 1e-5f);
    }
}

// ---------------------------------------------------------------------------
// Final: hn = (h - meanms[batch])*scalev[batch] + norm_b; out = hn @ Wf + bf
// In-place safe on h==out: each block stages its own 64 rows to LDS, syncs,
// then overwrites only those rows.
// ---------------------------------------------------------------------------
__global__ __launch_bounds__(256) void final_kernel(
    const float* __restrict__ h, const int* __restrict__ batch,
    const float* __restrict__ meanms, const float* __restrict__ scalev,
    const float* __restrict__ norm_b, const float* __restrict__ Wf,
    const float* __restrict__ bfinal, float* __restrict__ out, int Nn)
{
    extern __shared__ char smem[];
    __bf16* WT = (__bf16*)smem;                       // [128][136]
    __bf16* AT = (__bf16*)(smem + 128 * 136 * 2);     // [64][136]
    int tid = threadIdx.x;

    for (int i = tid; i < 16384; i += 256) { int k = i >> 7, n = i & 127; WT[n * 136 + k] = (__bf16)Wf[i]; }
    int r0 = blockIdx.x * 64;
    for (int i = tid; i < 64 * 128; i += 256) {
        int r = i >> 7, c = i & 127, gr = r0 + r;
        float v = 0.f;
        if (gr < Nn) {
            int g = batch[gr];
            v = (h[(size_t)gr * 128 + c] - meanms[g * 128 + c]) * scalev[g * 128 + c] + norm_b[c];
        }
        AT[r * 136 + c] = (__bf16)v;
    }
    __syncthreads();

    int wave = tid >> 6, lane = tid & 63, m = lane & 15, q = lane >> 4, kg = q * 8;
    f32x4 acc[8];
#pragma unroll
    for (int i = 0; i < 8; ++i) acc[i] = (f32x4){0.f, 0.f, 0.f, 0.f};
    for (int k0 = 0; k0 < 128; k0 += 32) {
        bf16x8 a = *(const bf16x8*)(AT + (wave * 16 + m) * 136 + k0 + kg);
#pragma unroll
        for (int ct = 0; ct < 8; ++ct) {
            bf16x8 b = *(const bf16x8*)(WT + (ct * 16 + m) * 136 + k0 + kg);
            acc[ct] = MFMA16(a, b, acc[ct]);
        }
    }
    int rb = r0 + wave * 16 + q * 4;
#pragma unroll
    for (int ct = 0; ct < 8; ++ct) {
        int col = ct * 16 + m;
        float bb = bfinal[col];
#pragma unroll
        for (int rg = 0; rg < 4; ++rg) {
            int r = rb + rg;
            if (r < Nn) out[(size_t)r * 128 + col] = acc[ct][rg] + bb;
        }
    }
}

// ---------------------------------------------------------------------------
extern "C" void kernel_launch(void* const* d_in, const int* in_sizes, int n_in,
                              void* d_out, int out_size, void* d_ws, size_t ws_size,
                              hipStream_t stream)
{
    const int N = in_sizes[0] / 128;
    const int E = in_sizes[3] / 2;

    const float* x         = (const float*)d_in[0];
    const float* feat1     = (const float*)d_in[1];
    const float* feat2     = (const float*)d_in[2];
    const int*   eidx      = (const int*)d_in[3];
    const int*   batch     = (const int*)d_in[4];
    const float* lin_w     = (const float*)d_in[5];
    const float* lin_b     = (const float*)d_in[6];
    const float* f1_w1     = (const float*)d_in[7];
    const float* f1_w2     = (const float*)d_in[8];
    const float* f2_w1     = (const float*)d_in[9];
    const float* f2_w2     = (const float*)d_in[10];
    const float* c1_rel_w  = (const float*)d_in[11];
    const float* c1_rel_b  = (const float*)d_in[12];
    const float* c1_root_w = (const float*)d_in[13];
    const float* c2_rel_w  = (const float*)d_in[14];
    const float* c2_rel_b  = (const float*)d_in[15];
    const float* c2_root_w = (const float*)d_in[16];
    const float* lin1_w    = (const float*)d_in[17];
    const float* lin1_b    = (const float*)d_in[18];
    const float* lin2_w    = (const float*)d_in[19];
    const float* lin2_b    = (const float*)d_in[20];
    const float* lincat_w  = (const float*)d_in[21];
    const float* lincat_b  = (const float*)d_in[22];
    const float* norm_w    = (const float*)d_in[23];
    const float* norm_b    = (const float*)d_in[24];
    const float* norm_ms   = (const float*)d_in[25];
    const float* lins_w    = (const float*)d_in[26];
    const float* lins_b    = (const float*)d_in[27];
    const float* final_w   = (const float*)d_in[28];
    const float* final_b   = (const float*)d_in[29];

    // Workspace: bf16 intermediates (51.2 MB) + norm stats (0.5 MB) +
    // edge sort arrays (N + 3E ints = 12.2 MB). d_out doubles as the f32
    // agg buffer (conv1/conv2) and then the f32 h buffer (lincat .. final).
    char* ws = (char*)d_ws;
    size_t nh = (size_t)N * 128;
    __bf16* xh     = (__bf16*)ws;                        // nh bf16
    __bf16* cbuf   = (__bf16*)(ws + nh * 2);             // nh bf16
    __bf16* h1     = (__bf16*)(ws + nh * 4);             // nh bf16
    __bf16* h2     = (__bf16*)(ws + nh * 6);             // nh bf16
    float*  meanms = (float*)(ws + nh * 8);              // 512*128 f32
    float*  scalev = (float*)(ws + nh * 8 + 512 * 128 * 4);
    char*   ip     = ws + nh * 8 + 512 * 128 * 4 * 2;
    int* wptr  = (int*)ip;                               // N ints
    int* sperm = (int*)(ip + (size_t)N * 4);             // E ints
    int* ssrc  = (int*)(ip + (size_t)N * 4 + (size_t)E * 4);
    int* sdst  = (int*)(ip + (size_t)N * 4 + (size_t)E * 8);
    float*  aggh   = (float*)d_out;                      // N*128 f32

    const int    nbN    = (N + 63) / 64;
    const int    nbE    = (E + 127) / 128;
    const int    nbES   = (E + 255) / 256;
    const size_t smemN1 = 136 * 128 * 2;                 // 34816
    const size_t smemN2 = 264 * 128 * 2;                 // 67584
    const size_t smemE  = 73216;
    const size_t smemF  = 128 * 136 * 2 + 64 * 136 * 2;  // 52224

    hipFuncSetAttribute((const void*)node_gemm, hipFuncAttributeMaxDynamicSharedMemorySize, (int)smemN2);
    hipFuncSetAttribute((const void*)&edge_conv<147, 160, 168>, hipFuncAttributeMaxDynamicSharedMemorySize, (int)smemE);
    hipFuncSetAttribute((const void*)&edge_conv<21, 32, 40>, hipFuncAttributeMaxDynamicSharedMemorySize, (int)smemE);
    hipFuncSetAttribute((const void*)final_kernel, hipFuncAttributeMaxDynamicSharedMemorySize, (int)smemF);

    // --- counting sort of edges by dst (reused by both convs) ---
    hipMemsetAsync(wptr, 0, (size_t)N * 4, stream);
    k_hist<<<nbES, 256, 0, stream>>>(eidx, wptr, E);
    k_scan<<<1, 1024, 0, stream>>>(wptr, N);
    k_scatter<<<nbES, 256, 0, stream>>>(eidx, wptr, sperm, ssrc, sdst, E);

    // xh = swish(x @ lin_w + lin_b)
    node_gemm<<<nbN, 256, smemN1, stream>>>(x, 1, nullptr, 0, lin_w, nullptr, lin_b,
                                            nullptr, 0, xh, 0, N, 1);
    // conv1 scatter into d_out
    hipMemsetAsync(aggh, 0, nh * 4, stream);
    edge_conv<147, 160, 168><<<nbE, 256, smemE, stream>>>(feat1, f1_w1, f1_w2, xh,
                                                          sperm, ssrc, sdst, aggh, E);
    // c1 = [agg|xh] @ [rel;root] + rel_b
    node_gemm<<<nbN, 256, smemN2, stream>>>(aggh, 1, xh, 0, c1_rel_w, c1_root_w, c1_rel_b,
                                            nullptr, 0, cbuf, 0, N, 0);
    // h1 = swish(c1 @ lin1_w + lin1_b)
    node_gemm<<<nbN, 256, smemN1, stream>>>(cbuf, 0, nullptr, 0, lin1_w, nullptr, lin1_b,
                                            nullptr, 0, h1, 0, N, 1);
    // conv2 scatter (reuse d_out)
    hipMemsetAsync(aggh, 0, nh * 4, stream);
    edge_conv<21, 32, 40><<<nbE, 256, smemE, stream>>>(feat2, f2_w1, f2_w2, xh,
                                                       sperm, ssrc, sdst, aggh, E);
    // c2
    node_gemm<<<nbN, 256, smemN2, stream>>>(aggh, 1, xh, 0, c2_rel_w, c2_root_w, c2_rel_b,
                                            nullptr, 0, cbuf, 0, N, 0);
    // h2
    node_gemm<<<nbN, 256, smemN1, stream>>>(cbuf, 0, nullptr, 0, lin2_w, nullptr, lin2_b,
                                            nullptr, 0, h2, 0, N, 1);
    // h = [h1|h2] @ lincat_w + lincat_b + xh  -> f32 into d_out (agg dead)
    node_gemm<<<nbN, 256, smemN2, stream>>>(h1, 0, h2, 0, lincat_w, lincat_w + 16384, lincat_b,
                                            xh, 0, aggh, 1, N, 0);
    // 3 residual swish lins (in place, f32)
    for (int i = 0; i < 3; ++i)
        node_gemm<<<nbN, 256, smemN1, stream>>>(aggh, 1, nullptr, 0, lins_w + i * 16384, nullptr,
                                                lins_b + i * 128, aggh, 1, aggh, 1, N, 1);
    // GraphNorm stats + fused norm/final GEMM (in-place on d_out)
    graph_stats<<<512, 256, 0, stream>>>(aggh, batch, norm_w, norm_ms, meanms, scalev, N);
    final_kernel<<<nbN, 256, smemF, stream>>>(aggh, batch, meanms, scalev, norm_b,
                                              final_w, final_b, aggh, N);
}